// Round 6
// baseline (217.531 us; speedup 1.0000x reference)
//
#include <hip/hip_runtime.h>

#define K_CLUSTERS 512
#define D_FEAT 64
#define ROWS_PER_BLOCK 64
#define THREADS 256
#define NCHUNK 8   // 512 clusters / 64-cluster chunks

typedef short bf16x8 __attribute__((ext_vector_type(8)));
typedef short bf16x4 __attribute__((ext_vector_type(4)));
typedef float f32x4 __attribute__((ext_vector_type(4)));

__device__ __forceinline__ unsigned short f32_to_bf16(float f) {
  unsigned int u = __float_as_uint(f);
  u += 0x7fffu + ((u >> 16) & 1u);   // RNE
  return (unsigned short)(u >> 16);
}
__device__ __forceinline__ float bf16_to_f32(unsigned short h) {
  return __uint_as_float(((unsigned int)h) << 16);
}

// Ring swizzle: chunk element index (6 bits) XOR key(row)<<3, key=(row>>1)&7.
// - b16 scatter writes (rows quad*4+r, c=wv*16+l16): keys distinct per quad ->
//   4 disjoint 16-elem windows -> 32 banks, 2 lanes/bank-dword (merged) = free.
// - b128 A-frag reads (row=rt*16+l16, k=kh*32+quad*8): 16 lanes -> 8 distinct
//   8-elem chunks x 2 lanes = 32 banks at 2 lanes/bank = free (m136).
#define WKEY(row) ((((unsigned)(row)) >> 1) & 7u)

// ---------------- prep: one wave per cluster, lane = feature. Coalesced.
__global__ void kmeans_prep(const float* __restrict__ cent,
                            unsigned short* __restrict__ chi,   // [K][D] hi
                            unsigned short* __restrict__ clo,   // [K][D] lo
                            unsigned short* __restrict__ cthi,  // [D][K] hi
                            float* __restrict__ csqs) {         // [K], 10*log2e*|c|^2
  const int wv = threadIdx.x >> 6;
  const int lane = threadIdx.x & 63;
  const int k = blockIdx.x * 4 + wv;    // 128 blocks -> k in [0,512)
  const int f = lane;
  float v = cent[k * D_FEAT + f];
  unsigned short h = f32_to_bf16(v);
  float rem = v - bf16_to_f32(h);
  unsigned short l = f32_to_bf16(rem);
  chi[k * D_FEAT + f] = h;
  clo[k * D_FEAT + f] = l;
  cthi[f * K_CLUSTERS + k] = h;
  float s = v * v;
#pragma unroll
  for (int d = 1; d < 64; d <<= 1) s += __shfl_xor(s, d, 64);
  if (lane == 0) csqs[k] = s * 14.42695040888963f;  // 10 * log2(e)
}

// ---------------- main: 64 rows/block, single streaming K-loop.
// Per 64-cluster chunk: scores (cluster-split, hi/lo-split bf16, 24 MFMA/wave)
// -> exp2 (no max pass; logits bounded) -> bf16 weights into a 2x8KB swizzled
// LDS ring -> barrier -> mixture update (feat-split, hi-c only, 8 MFMA/wave)
// while next chunk's global loads are in flight. srow accumulated in regs,
// reduced once at the end. 1 barrier/chunk; double buffer makes it safe.
__global__ __launch_bounds__(THREADS, 3) void kmeans_main(
    const float* __restrict__ x,
    const unsigned short* __restrict__ chi,
    const unsigned short* __restrict__ clo,
    const unsigned short* __restrict__ cthi,
    const float* __restrict__ csqs,
    float* __restrict__ out) {
  // LDS 18432 B: ring = 2 x [64 rows][64 c] bf16 (16384 B) at offset 0;
  // redsum [64][4] f32 at 16384. x staging xh/xl [64][72] (18432 B) aliases
  // everything -- it is dead after the A-frag loads (fenced by barrier).
  __shared__ __attribute__((aligned(16))) unsigned char smem[18432];
  unsigned short* xh   = (unsigned short*)smem;        // [64][72]
  unsigned short* xl   = xh + 64 * 72;                 // [64][72]
  unsigned short* ring = (unsigned short*)smem;        // 2 x [64][64]
  float* redsum = (float*)(smem + 16384);              // [64][4]

  const int tid  = threadIdx.x;
  const int wv   = tid >> 6;
  const int lane = tid & 63;
  const int l16  = lane & 15;
  const int quad = lane >> 4;
  const long long rowbase = (long long)blockIdx.x * ROWS_PER_BLOCK;

  // ---- stage x -> xh/xl (coalesced float4 loads, hi/lo bf16 split) ----
  {
    int r  = tid >> 2;             // 0..63
    int f0 = (tid & 3) * 16;       // 0,16,32,48
    const float4* src4 = (const float4*)(x + (rowbase + r) * D_FEAT + f0);
#pragma unroll
    for (int i = 0; i < 4; ++i) {
      float4 v = src4[i];
      float vv[4] = {v.x, v.y, v.z, v.w};
      bf16x4 hi, lo;
#pragma unroll
      for (int j = 0; j < 4; ++j) {
        unsigned short h = f32_to_bf16(vv[j]);
        hi[j] = (short)h;
        lo[j] = (short)f32_to_bf16(vv[j] - bf16_to_f32(h));
      }
      *(bf16x4*)(xh + r * 72 + f0 + i * 4) = hi;
      *(bf16x4*)(xl + r * 72 + f0 + i * 4) = lo;
    }
  }
  __syncthreads();   // staging visible

  // ---- A fragments, 4 row-tiles: A[m=l16][k=quad*8+j], 64 VGPRs ----
  bf16x8 ah[4][2], al[4][2];
#pragma unroll
  for (int rt = 0; rt < 4; ++rt)
#pragma unroll
    for (int ks = 0; ks < 2; ++ks) {
      ah[rt][ks] = *(const bf16x8*)(xh + (rt * 16 + l16) * 72 + ks * 32 + quad * 8);
      al[rt][ks] = *(const bf16x8*)(xl + (rt * 16 + l16) * 72 + ks * 32 + quad * 8);
    }
  __syncthreads();   // staging dead -> ring writable

  const int bko  = quad * 8;
  const int myc  = wv * 16 + l16;            // score cluster-in-chunk
  const int feat = wv * 16 + l16;            // mixture feature
  const unsigned short* ctbase = cthi + feat * K_CLUSTERS;

  f32x4 srow[4] = {{0.f,0.f,0.f,0.f},{0.f,0.f,0.f,0.f},{0.f,0.f,0.f,0.f},{0.f,0.f,0.f,0.f}};
  f32x4 oacc[4] = {{0.f,0.f,0.f,0.f},{0.f,0.f,0.f,0.f},{0.f,0.f,0.f,0.f},{0.f,0.f,0.f,0.f}};

  // ---- prefetch chunk 0 ----
  bf16x8 sb0, sb1, sb2, sb3;   // score B: chi k0, chi k1, clo k0, clo k1
  float  scs;
  bf16x8 ct0, ct1;             // mixture B: cthi kh0, kh1
  {
    const unsigned short* ph = chi + myc * 64;
    const unsigned short* pl = clo + myc * 64;
    sb0 = *(const bf16x8*)(ph + bko);
    sb1 = *(const bf16x8*)(ph + 32 + bko);
    sb2 = *(const bf16x8*)(pl + bko);
    sb3 = *(const bf16x8*)(pl + 32 + bko);
    scs = csqs[myc];
    ct0 = *(const bf16x8*)(ctbase + bko);
    ct1 = *(const bf16x8*)(ctbase + 32 + bko);
  }

#pragma unroll
  for (int c8 = 0; c8 < NCHUNK; ++c8) {
    bf16x8 b0 = sb0, b1 = sb1, b2 = sb2, b3 = sb3;
    float  cs = scs;
    bf16x8 cb0 = ct0, cb1 = ct1;
    if (c8 < NCHUNK - 1) {   // prefetch chunk c8+1 (in flight across barrier)
      int cl = (c8 + 1) * 64 + myc;
      sb0 = *(const bf16x8*)(chi + cl * 64 + bko);
      sb1 = *(const bf16x8*)(chi + cl * 64 + 32 + bko);
      sb2 = *(const bf16x8*)(clo + cl * 64 + bko);
      sb3 = *(const bf16x8*)(clo + cl * 64 + 32 + bko);
      scs = csqs[cl];
      ct0 = *(const bf16x8*)(ctbase + (c8 + 1) * 64 + bko);
      ct1 = *(const bf16x8*)(ctbase + (c8 + 1) * 64 + 32 + bko);
    }

    unsigned short* buf = ring + (c8 & 1) * 4096;
    const unsigned cloc = (unsigned)myc;

    // ---- scores: 16 clusters (this wave) x 64 rows ----
#pragma unroll
    for (int rt = 0; rt < 4; ++rt) {
      f32x4 a = {0.f, 0.f, 0.f, 0.f};
      a = __builtin_amdgcn_mfma_f32_16x16x32_bf16(ah[rt][0], b0, a, 0, 0, 0);
      a = __builtin_amdgcn_mfma_f32_16x16x32_bf16(ah[rt][1], b1, a, 0, 0, 0);
      a = __builtin_amdgcn_mfma_f32_16x16x32_bf16(ah[rt][0], b2, a, 0, 0, 0);
      a = __builtin_amdgcn_mfma_f32_16x16x32_bf16(ah[rt][1], b3, a, 0, 0, 0);
      a = __builtin_amdgcn_mfma_f32_16x16x32_bf16(al[rt][0], b0, a, 0, 0, 0);
      a = __builtin_amdgcn_mfma_f32_16x16x32_bf16(al[rt][1], b1, a, 0, 0, 0);
      // w = 2^(20*log2e*cross - 10*log2e*|c|^2); row constant cancels in softmax
#pragma unroll
      for (int r = 0; r < 4; ++r) {
        float e = __builtin_amdgcn_exp2f(fmaf(28.85390081777927f, a[r], -cs));
        srow[rt][r] += e;
        int row = rt * 16 + quad * 4 + r;
        buf[row * 64 + (cloc ^ (WKEY(row) << 3))] = f32_to_bf16(e);
      }
    }
    __syncthreads();   // W chunk visible (single barrier/chunk: dbuf-safe)

    // ---- mixture update: this wave's 16 feats x 64 rows, k = 64 clusters ----
#pragma unroll
    for (int kh = 0; kh < 2; ++kh) {
      bf16x8 cb = kh ? cb1 : cb0;
      const unsigned ko = (unsigned)(kh * 32 + quad * 8);
#pragma unroll
      for (int rt = 0; rt < 4; ++rt) {
        int row = rt * 16 + l16;
        bf16x8 aw = *(const bf16x8*)(buf + row * 64 + (ko ^ (WKEY(row) << 3)));
        oacc[rt] = __builtin_amdgcn_mfma_f32_16x16x32_bf16(aw, cb, oacc[rt], 0, 0, 0);
      }
    }
  }

  // ---- row-sum reduction: lanes (l16) -> LDS (waves) ----
#pragma unroll
  for (int d = 1; d < 16; d <<= 1)
#pragma unroll
    for (int rt = 0; rt < 4; ++rt)
#pragma unroll
      for (int r = 0; r < 4; ++r) srow[rt][r] += __shfl_xor(srow[rt][r], d, 64);
  if (l16 == 0) {
#pragma unroll
    for (int rt = 0; rt < 4; ++rt)
#pragma unroll
      for (int r = 0; r < 4; ++r)
        redsum[(rt * 16 + quad * 4 + r) * 4 + wv] = srow[rt][r];
  }
  __syncthreads();

  // ---- epilogue: normalize, store (16 lanes = 16 consecutive feats) ----
#pragma unroll
  for (int rt = 0; rt < 4; ++rt) {
#pragma unroll
    for (int r = 0; r < 4; ++r) {
      int row = rt * 16 + quad * 4 + r;
      f32x4 s4 = *(const f32x4*)(redsum + row * 4);
      float iv = __builtin_amdgcn_rcpf((s4[0] + s4[1]) + (s4[2] + s4[3]));
      out[(rowbase + row) * D_FEAT + feat] = oacc[rt][r] * iv;
    }
  }
}

extern "C" void kernel_launch(void* const* d_in, const int* in_sizes, int n_in,
                              void* d_out, int out_size, void* d_ws, size_t ws_size,
                              hipStream_t stream) {
  const float* x    = (const float*)d_in[0];
  const float* cent = (const float*)d_in[1];
  float* out        = (float*)d_out;

  unsigned short* chi  = (unsigned short*)d_ws;
  unsigned short* clo  = chi  + K_CLUSTERS * D_FEAT;
  unsigned short* cthi = clo  + K_CLUSTERS * D_FEAT;
  float*          csqs = (float*)(cthi + K_CLUSTERS * D_FEAT);

  kmeans_prep<<<K_CLUSTERS / 4, THREADS, 0, stream>>>(
      cent, chi, clo, cthi, csqs);

  int nrows = in_sizes[0] / D_FEAT;  // 131072
  kmeans_main<<<nrows / ROWS_PER_BLOCK, THREADS, 0, stream>>>(
      x, chi, clo, cthi, csqs, out);
}

// Round 9
// 216.142 us; speedup vs baseline: 1.0064x; 1.0064x over previous
//
#include <hip/hip_runtime.h>

#define K_CLUSTERS 512
#define D_FEAT 64
#define ROWS_PER_BLOCK 64
#define THREADS 512

typedef short bf16x8 __attribute__((ext_vector_type(8)));
typedef short bf16x4 __attribute__((ext_vector_type(4)));
typedef float f32x4 __attribute__((ext_vector_type(4)));

__device__ __forceinline__ unsigned short f32_to_bf16(float f) {
  unsigned int u = __float_as_uint(f);
  u += 0x7fffu + ((u >> 16) & 1u);   // RNE
  return (unsigned short)(u >> 16);
}
__device__ __forceinline__ float bf16_to_f32(unsigned short h) {
  return __uint_as_float(((unsigned int)h) << 16);
}

// W swizzle (R4-validated): elem = c ^ (((row>>1)&7)<<3).
// Writes (rows quad*4+r, 16 consec c): quads land in 4 disjoint 16-elem
// windows -> 32 banks, <=2 b16/dword. Reads (rows rt*16+l16, b128): 8
// distinct keys x 2 lanes -> 32 banks, 2 lanes/bank = free (m136).
#define WSWZ(row) (((((unsigned)(row)) >> 1) & 7u) << 3)

// ---------------- prep: one wave per cluster, lane = feature. Coalesced.
__global__ void kmeans_prep(const float* __restrict__ cent,
                            unsigned short* __restrict__ chi,   // [K][D] hi
                            unsigned short* __restrict__ clo,   // [K][D] lo
                            unsigned short* __restrict__ cthi,  // [D][K] hi
                            float* __restrict__ csqs) {         // [K], 10*log2e*|c|^2
  const int wv = threadIdx.x >> 6;
  const int lane = threadIdx.x & 63;
  const int k = blockIdx.x * 4 + wv;    // 128 blocks -> k in [0,512)
  const int f = lane;
  float v = cent[k * D_FEAT + f];
  unsigned short h = f32_to_bf16(v);
  float rem = v - bf16_to_f32(h);
  unsigned short l = f32_to_bf16(rem);
  chi[k * D_FEAT + f] = h;
  clo[k * D_FEAT + f] = l;
  cthi[f * K_CLUSTERS + k] = h;
  float s = v * v;
#pragma unroll
  for (int d = 1; d < 64; d <<= 1) s += __shfl_xor(s, d, 64);
  if (lane == 0) csqs[k] = s * 14.42695040888963f;  // 10 * log2(e)
}

// ---------------- main: 64 rows/block, 512 threads (8 waves), 2 blocks/CU
// -> 16 waves/CU (2x R4's latency hiding at identical per-wave intensity).
// Phase A: wave owns 64 clusters x 64 rows (4 t-iters, depth-2 prefetch),
// hi/lo-split bf16 scores, exp2 (no max pass: logits bounded), bf16 weights
// into swizzled LDS W. Phase C: wave owns (row-tile, feat-half) = 16 rows x
// 32 feats, K=512, hi-centroids only (validated: absmax 0.00195 < 5.16e-3).
__global__ __launch_bounds__(THREADS, 4) void kmeans_main(
    const float* __restrict__ x,
    const unsigned short* __restrict__ chi,
    const unsigned short* __restrict__ clo,
    const unsigned short* __restrict__ cthi,
    const float* __restrict__ csqs,
    float* __restrict__ out) {
  // LDS 67584 B: W [64][512] bf16 (65536, swizzled) + redsum [64][8] f32
  // (2048). x staging xh/xl [64][72] (18432) aliases head of W (dead after
  // A-frag loads, fenced by barrier 2). 2 blocks/CU (135 KB of 160 KB).
  __shared__ __attribute__((aligned(16))) unsigned char smem[65536 + 2048];
  unsigned short* xh = (unsigned short*)smem;            // [64][72]
  unsigned short* xl = xh + 64 * 72;                     // [64][72]
  unsigned short* W  = (unsigned short*)smem;            // [64][512] swizzled
  float* redsum = (float*)(smem + 65536);                // [64][8]

  const int tid  = threadIdx.x;
  const int wv   = tid >> 6;                             // 0..7
  const int lane = tid & 63;
  const int l16  = lane & 15;
  const int quad = lane >> 4;
  const long long rowbase = (long long)blockIdx.x * ROWS_PER_BLOCK;

  // ---- stage x -> xh/xl (coalesced float4 loads, hi/lo bf16 split) ----
  {
    int r  = tid >> 3;             // 0..63
    int f0 = (tid & 7) * 8;        // 0..56
    const float4* src4 = (const float4*)(x + (rowbase + r) * D_FEAT + f0);
#pragma unroll
    for (int i = 0; i < 2; ++i) {
      float4 v = src4[i];
      float vv[4] = {v.x, v.y, v.z, v.w};
      bf16x4 hi, lo;
#pragma unroll
      for (int j = 0; j < 4; ++j) {
        unsigned short h = f32_to_bf16(vv[j]);
        hi[j] = (short)h;
        lo[j] = (short)f32_to_bf16(vv[j] - bf16_to_f32(h));
      }
      *(bf16x4*)(xh + r * 72 + f0 + i * 4) = hi;
      *(bf16x4*)(xl + r * 72 + f0 + i * 4) = lo;
    }
  }
  __syncthreads();   // staging visible

  // ---- A fragments, 4 row-tiles: A[m=l16][k=quad*8+j], 64 VGPRs ----
  bf16x8 ah[4][2], al[4][2];
#pragma unroll
  for (int rt = 0; rt < 4; ++rt)
#pragma unroll
    for (int ks = 0; ks < 2; ++ks) {
      ah[rt][ks] = *(const bf16x8*)(xh + (rt * 16 + l16) * 72 + ks * 32 + quad * 8);
      al[rt][ks] = *(const bf16x8*)(xl + (rt * 16 + l16) * 72 + ks * 32 + quad * 8);
    }
  __syncthreads();   // xh/xl dead -> W region writable

  // ---- Phase A: wave's 64-cluster slice x 64 rows, depth-2 prefetch ----
  const int cbase = wv * 64;
  const int bko = quad * 8;
  f32x4 srow[4] = {{0.f,0.f,0.f,0.f},{0.f,0.f,0.f,0.f},{0.f,0.f,0.f,0.f},{0.f,0.f,0.f,0.f}};

  bf16x8 pbh0[2], pbh1[2], pbl0[2], pbl1[2];
  float pcs[2];
#pragma unroll
  for (int p = 0; p < 2; ++p) {
    int cl = cbase + p * 16 + l16;
    pbh0[p] = *(const bf16x8*)(chi + cl * 64 + bko);
    pbh1[p] = *(const bf16x8*)(chi + cl * 64 + 32 + bko);
    pbl0[p] = *(const bf16x8*)(clo + cl * 64 + bko);
    pbl1[p] = *(const bf16x8*)(clo + cl * 64 + 32 + bko);
    pcs[p]  = csqs[cl];
  }

#pragma unroll
  for (int t = 0; t < 4; ++t) {
    const int sl = t & 1;
    bf16x8 cbh0 = pbh0[sl], cbh1 = pbh1[sl], cbl0 = pbl0[sl], cbl1 = pbl1[sl];
    float ccs = pcs[sl];
    if (t < 2) {   // prefetch t+2
      int cl = cbase + (t + 2) * 16 + l16;
      pbh0[sl] = *(const bf16x8*)(chi + cl * 64 + bko);
      pbh1[sl] = *(const bf16x8*)(chi + cl * 64 + 32 + bko);
      pbl0[sl] = *(const bf16x8*)(clo + cl * 64 + bko);
      pbl1[sl] = *(const bf16x8*)(clo + cl * 64 + 32 + bko);
      pcs[sl]  = csqs[cl];
    }
    const int c = cbase + t * 16 + l16;
#pragma unroll
    for (int rt = 0; rt < 4; ++rt) {
      f32x4 a = {0.f, 0.f, 0.f, 0.f};
      a = __builtin_amdgcn_mfma_f32_16x16x32_bf16(ah[rt][0], cbh0, a, 0, 0, 0);
      a = __builtin_amdgcn_mfma_f32_16x16x32_bf16(ah[rt][1], cbh1, a, 0, 0, 0);
      a = __builtin_amdgcn_mfma_f32_16x16x32_bf16(ah[rt][0], cbl0, a, 0, 0, 0);
      a = __builtin_amdgcn_mfma_f32_16x16x32_bf16(ah[rt][1], cbl1, a, 0, 0, 0);
      a = __builtin_amdgcn_mfma_f32_16x16x32_bf16(al[rt][0], cbh0, a, 0, 0, 0);
      a = __builtin_amdgcn_mfma_f32_16x16x32_bf16(al[rt][1], cbh1, a, 0, 0, 0);
      // w = 2^(20*log2e*cross - 10*log2e*|c|^2); row constant cancels
#pragma unroll
      for (int r = 0; r < 4; ++r) {
        float e = exp2f(fmaf(28.85390081777927f, a[r], -ccs));
        srow[rt][r] += e;
        int row = rt * 16 + quad * 4 + r;
        W[row * 512 + ((unsigned)c ^ WSWZ(row))] = f32_to_bf16(e);
      }
    }
  }

  // ---- per-wave partial row sums -> LDS ----
#pragma unroll
  for (int d = 1; d < 16; d <<= 1)
#pragma unroll
    for (int rt = 0; rt < 4; ++rt)
#pragma unroll
      for (int r = 0; r < 4; ++r) srow[rt][r] += __shfl_xor(srow[rt][r], d, 64);
  if (l16 == 0) {
#pragma unroll
    for (int rt = 0; rt < 4; ++rt)
#pragma unroll
      for (int r = 0; r < 4; ++r)
        redsum[(rt * 16 + quad * 4 + r) * 8 + wv] = srow[rt][r];
  }
  __syncthreads();   // W + redsum visible to all waves

  // ---- Phase C: wave owns (row-tile rt, feat-half fh): 16 rows x 32 feats ----
  const int crt = wv & 3;
  const int fh  = wv >> 2;
  const int arow = crt * 16 + l16;
  const unsigned short* Wrow = W + arow * 512;
  const unsigned swz = WSWZ(arow);
  const unsigned short* ct0p = cthi + (fh * 32 + l16) * K_CLUSTERS;
  const unsigned short* ct1p = cthi + (fh * 32 + 16 + l16) * K_CLUSTERS;
  f32x4 oacc[2] = {{0.f,0.f,0.f,0.f},{0.f,0.f,0.f,0.f}};

  bf16x8 qb0[2], qb1[2];
#pragma unroll
  for (int p = 0; p < 2; ++p) {
    qb0[p] = *(const bf16x8*)(ct0p + p * 32 + bko);
    qb1[p] = *(const bf16x8*)(ct1p + p * 32 + bko);
  }
#pragma unroll
  for (int ks = 0; ks < 16; ++ks) {
    const int sl = ks & 1;
    bf16x8 b0 = qb0[sl], b1 = qb1[sl];
    if (ks < 14) {   // prefetch ks+2
      qb0[sl] = *(const bf16x8*)(ct0p + (ks + 2) * 32 + bko);
      qb1[sl] = *(const bf16x8*)(ct1p + (ks + 2) * 32 + bko);
    }
    bf16x8 aw = *(const bf16x8*)(Wrow + (((unsigned)(ks * 32) + bko) ^ swz));
    oacc[0] = __builtin_amdgcn_mfma_f32_16x16x32_bf16(aw, b0, oacc[0], 0, 0, 0);
    oacc[1] = __builtin_amdgcn_mfma_f32_16x16x32_bf16(aw, b1, oacc[1], 0, 0, 0);
  }

  // ---- epilogue: normalize, store (16 lanes = 16 consecutive feats) ----
#pragma unroll
  for (int r = 0; r < 4; ++r) {
    int row = crt * 16 + quad * 4 + r;
    f32x4 sa = *(const f32x4*)(redsum + row * 8);
    f32x4 sb = *(const f32x4*)(redsum + row * 8 + 4);
    float iv = __builtin_amdgcn_rcpf(((sa[0] + sa[1]) + (sa[2] + sa[3])) +
                                     ((sb[0] + sb[1]) + (sb[2] + sb[3])));
    float* op = out + (rowbase + row) * D_FEAT + fh * 32 + l16;
    op[0]  = oacc[0][r] * iv;
    op[16] = oacc[1][r] * iv;
  }
}

extern "C" void kernel_launch(void* const* d_in, const int* in_sizes, int n_in,
                              void* d_out, int out_size, void* d_ws, size_t ws_size,
                              hipStream_t stream) {
  const float* x    = (const float*)d_in[0];
  const float* cent = (const float*)d_in[1];
  float* out        = (float*)d_out;

  unsigned short* chi  = (unsigned short*)d_ws;
  unsigned short* clo  = chi  + K_CLUSTERS * D_FEAT;
  unsigned short* cthi = clo  + K_CLUSTERS * D_FEAT;
  float*          csqs = (float*)(cthi + K_CLUSTERS * D_FEAT);

  kmeans_prep<<<K_CLUSTERS / 4, 256, 0, stream>>>(
      cent, chi, clo, cthi, csqs);

  int nrows = in_sizes[0] / D_FEAT;  // 131072
  kmeans_main<<<nrows / ROWS_PER_BLOCK, THREADS, 0, stream>>>(
      x, chi, clo, cthi, csqs, out);
}